// Round 1
// baseline (2276.409 us; speedup 1.0000x reference)
//
#include <hip/hip_runtime.h>
#include <float.h>

#define T_TOTAL (16 * 2048)   // 32768 tokens
#define KC      8192          // codebook entries
#define DIM     256           // embedding dim
#define BT      64            // tokens per block
#define BK      128           // codes per K-chunk
#define BD      32            // D-chunk staged in LDS
#define LROW    (BD + 4)      // padded LDS row (36 floats -> bank stride 4, 2-way alias = free)

#define LOSS_IDX  ((size_t)T_TOTAL * DIM)      // 8388608
#define USAGE_IDX (LOSS_IDX + 1)               // 8388609

// ---------------------------------------------------------------------------
// init: zero usage flags + the two scalar outputs (d_out/d_ws are 0xAA-poisoned)
__global__ __launch_bounds__(256) void vq_init(int* __restrict__ flags,
                                               float* __restrict__ out) {
    int i = blockIdx.x * 256 + threadIdx.x;
    if (i < KC) flags[i] = 0;
    if (i == 0) { out[LOSS_IDX] = 0.0f; out[USAGE_IDX] = 0.0f; }
}

// ---------------------------------------------------------------------------
// w2[k] = sum_d codebook[k][d]^2   (one wave per row, float4 loads)
__global__ __launch_bounds__(256) void vq_w2(const float* __restrict__ cb,
                                             float* __restrict__ w2) {
    int lane = threadIdx.x & 63;
    int wv = threadIdx.x >> 6;
    int k = blockIdx.x * 4 + wv;
    const float4 c = *(const float4*)(cb + (size_t)k * DIM + lane * 4);
    float s = c.x * c.x + c.y * c.y + c.z * c.z + c.w * c.w;
    #pragma unroll
    for (int m = 32; m >= 1; m >>= 1) s += __shfl_xor(s, m);
    if (lane == 0) w2[k] = s;
}

// ---------------------------------------------------------------------------
// main fused kernel: distance-GEMM + argmin + gather + loss partial + flags
// block = 256 threads (tx = tid&15 -> codes, ty = tid>>4 -> tokens)
// per thread: 4 tokens (ty + 16*i) x 8 codes (kb + tx + 16*j)
__global__ __launch_bounds__(256) void vq_main(const float* __restrict__ z_e,
                                               const float* __restrict__ cb,
                                               const float* __restrict__ w2,
                                               float* __restrict__ out,
                                               int* __restrict__ flags) {
    __shared__ float zs[BT][LROW];
    __shared__ float cs[BK][LROW];
    __shared__ int   idxs[BT];
    __shared__ float wls[4];

    const int tid = threadIdx.x;
    const int tx = tid & 15;
    const int ty = tid >> 4;
    const int tblock = blockIdx.x * BT;

    float best[4];
    int   bidx[4];
    #pragma unroll
    for (int i = 0; i < 4; ++i) { best[i] = FLT_MAX; bidx[i] = 0; }

    for (int kb = 0; kb < KC; kb += BK) {
        float acc[4][8];
        #pragma unroll
        for (int i = 0; i < 4; ++i)
            #pragma unroll
            for (int j = 0; j < 8; ++j) acc[i][j] = 0.0f;

        for (int db = 0; db < DIM; db += BD) {
            __syncthreads();   // protect LDS from previous iteration's readers
            // stage z tile: BT x BD = 512 float4, 2 per thread
            #pragma unroll
            for (int q = 0; q < 2; ++q) {
                int f = tid + 256 * q;
                int r = f >> 3, c4 = f & 7;
                float4 v = *(const float4*)(z_e + (size_t)(tblock + r) * DIM + db + c4 * 4);
                *(float4*)&zs[r][c4 * 4] = v;
            }
            // stage c tile: BK x BD = 1024 float4, 4 per thread
            #pragma unroll
            for (int q = 0; q < 4; ++q) {
                int f = tid + 256 * q;
                int r = f >> 3, c4 = f & 7;
                float4 v = *(const float4*)(cb + (size_t)(kb + r) * DIM + db + c4 * 4);
                *(float4*)&cs[r][c4 * 4] = v;
            }
            __syncthreads();

            #pragma unroll
            for (int d = 0; d < BD; d += 4) {
                float4 zf[4], cf[8];
                #pragma unroll
                for (int i = 0; i < 4; ++i) zf[i] = *(const float4*)&zs[ty + 16 * i][d];
                #pragma unroll
                for (int j = 0; j < 8; ++j) cf[j] = *(const float4*)&cs[tx + 16 * j][d];
                #pragma unroll
                for (int i = 0; i < 4; ++i)
                    #pragma unroll
                    for (int j = 0; j < 8; ++j) {
                        acc[i][j] = fmaf(zf[i].x, cf[j].x, acc[i][j]);
                        acc[i][j] = fmaf(zf[i].y, cf[j].y, acc[i][j]);
                        acc[i][j] = fmaf(zf[i].z, cf[j].z, acc[i][j]);
                        acc[i][j] = fmaf(zf[i].w, cf[j].w, acc[i][j]);
                    }
            }
        }

        // argmin update: score = w2[k] - 2*dot  (x2 is per-token constant)
        #pragma unroll
        for (int j = 0; j < 8; ++j) {
            int k = kb + tx + 16 * j;
            float w2k = w2[k];
            #pragma unroll
            for (int i = 0; i < 4; ++i) {
                float s = fmaf(-2.0f, acc[i][j], w2k);
                if (s < best[i]) { best[i] = s; bidx[i] = k; }  // strict < : lowest k wins in-thread
            }
        }
    }

    // reduce (best, bidx) across the 16 tx lanes (within-wave), tie -> lower idx
    #pragma unroll
    for (int m = 1; m < 16; m <<= 1) {
        #pragma unroll
        for (int i = 0; i < 4; ++i) {
            float ob = __shfl_xor(best[i], m);
            int   oi = __shfl_xor(bidx[i], m);
            if (ob < best[i] || (ob == best[i] && oi < bidx[i])) { best[i] = ob; bidx[i] = oi; }
        }
    }

    __syncthreads();   // all lanes done reading cs/zs before reuse of LDS + idx publish
    if (tx == 0) {
        #pragma unroll
        for (int i = 0; i < 4; ++i) {
            idxs[ty + 16 * i] = bidx[i];
            flags[bidx[i]] = 1;   // benign race: all writers store 1
        }
    }
    __syncthreads();

    // gather z_q rows + fused loss partial: one wave per token row (64 lanes x float4 = 256)
    const int lane = tid & 63;
    const int wv = tid >> 6;
    float lsum = 0.0f;
    for (int t = wv; t < BT; t += 4) {
        int k = idxs[t];
        float4 c = *(const float4*)(cb + (size_t)k * DIM + lane * 4);
        float4 z = *(const float4*)(z_e + (size_t)(tblock + t) * DIM + lane * 4);
        float dx = z.x - c.x, dy = z.y - c.y, dz = z.z - c.z, dw = z.w - c.w;
        lsum += dx * dx + dy * dy + dz * dz + dw * dw;
        *(float4*)(out + (size_t)(tblock + t) * DIM + lane * 4) = c;
    }
    #pragma unroll
    for (int m = 32; m >= 1; m >>= 1) lsum += __shfl_xor(lsum, m);
    if (lane == 0) wls[wv] = lsum;
    __syncthreads();
    if (tid == 0) {
        float blocksum = wls[0] + wls[1] + wls[2] + wls[3];
        // loss = codebook_loss + 0.25*commitment = 1.25 * mean(diff^2)
        atomicAdd(out + LOSS_IDX, blocksum * (1.25f / (float)LOSS_IDX));
    }
}

// ---------------------------------------------------------------------------
// usage = (#flags set) / KC, single block
__global__ __launch_bounds__(256) void vq_usage(const int* __restrict__ flags,
                                                float* __restrict__ out) {
    __shared__ int ws[4];
    int tid = threadIdx.x;
    int s = 0;
    for (int i = tid; i < KC; i += 256) s += flags[i];
    #pragma unroll
    for (int m = 32; m >= 1; m >>= 1) s += __shfl_xor(s, m);
    if ((tid & 63) == 0) ws[tid >> 6] = s;
    __syncthreads();
    if (tid == 0) out[USAGE_IDX] = (float)(ws[0] + ws[1] + ws[2] + ws[3]) / (float)KC;
}

// ---------------------------------------------------------------------------
extern "C" void kernel_launch(void* const* d_in, const int* in_sizes, int n_in,
                              void* d_out, int out_size, void* d_ws, size_t ws_size,
                              hipStream_t stream) {
    (void)in_sizes; (void)n_in; (void)out_size; (void)ws_size;
    const float* z_e = (const float*)d_in[0];
    const float* cb  = (const float*)d_in[1];
    float* out = (float*)d_out;
    float* w2   = (float*)d_ws;                       // 8192 floats
    int*  flags = (int*)((char*)d_ws + KC * sizeof(float));  // 8192 ints

    vq_init<<<KC / 256, 256, 0, stream>>>(flags, out);
    vq_w2<<<KC / 4, 256, 0, stream>>>(cb, w2);
    vq_main<<<T_TOTAL / BT, 256, 0, stream>>>(z_e, cb, w2, out, flags);
    vq_usage<<<1, 256, 0, stream>>>(flags, out);
}

// Round 2
// 407.101 us; speedup vs baseline: 5.5918x; 5.5918x over previous
//
#include <hip/hip_runtime.h>
#include <float.h>

#define T_TOTAL (16 * 2048)   // 32768 tokens
#define KC      8192          // codebook entries
#define DIM     256           // embedding dim

#define LOSS_IDX  ((size_t)T_TOTAL * DIM)      // 8388608
#define USAGE_IDX (LOSS_IDX + 1)               // 8388609

typedef short  s16x8 __attribute__((ext_vector_type(8)));
typedef float  f32x4 __attribute__((ext_vector_type(4)));

// ws layout (bytes):
//   packed u64[32768]   @ 0            (262144)
//   w2     f32[8192]    @ 262144       (32768)
//   flags  i32[8192]    @ 294912       (32768)
//   z_bf   u16[32768*256] @ 327680     (16777216)
//   cb_bf  u16[8192*256]  @ 17104896   (4194304)   total ~20.3 MB
#define WS_PACKED 0
#define WS_W2     262144
#define WS_FLAGS  294912
#define WS_ZBF    327680
#define WS_CBF    17104896

__device__ __forceinline__ unsigned short f2bf(float f) {
    unsigned int u = __float_as_uint(f);
    u += 0x7FFFu + ((u >> 16) & 1u);   // RTNE
    return (unsigned short)(u >> 16);
}

// ---------------------------------------------------------------------------
__global__ __launch_bounds__(256) void vq_init(unsigned long long* __restrict__ packed,
                                               int* __restrict__ flags,
                                               float* __restrict__ out) {
    int i = blockIdx.x * 256 + threadIdx.x;   // 32768 threads
    packed[i] = ~0ULL;
    if (i < KC) flags[i] = 0;
    if (i == 0) { out[LOSS_IDX] = 0.0f; out[USAGE_IDX] = 0.0f; }
}

// fp32 -> bf16 (RTNE), 8 elements/thread, 16B stores
__global__ __launch_bounds__(256) void vq_cvt(const float* __restrict__ src,
                                              unsigned short* __restrict__ dst) {
    int i = (blockIdx.x * 256 + threadIdx.x) * 8;
    float4 a = *(const float4*)(src + i);
    float4 b = *(const float4*)(src + i + 4);
    uint4 o;
    o.x = (unsigned)f2bf(a.x) | ((unsigned)f2bf(a.y) << 16);
    o.y = (unsigned)f2bf(a.z) | ((unsigned)f2bf(a.w) << 16);
    o.z = (unsigned)f2bf(b.x) | ((unsigned)f2bf(b.y) << 16);
    o.w = (unsigned)f2bf(b.z) | ((unsigned)f2bf(b.w) << 16);
    *(uint4*)(dst + i) = o;
}

// w2[k] = sum_d cb[k][d]^2 (exact fp32), one wave per row
__global__ __launch_bounds__(256) void vq_w2(const float* __restrict__ cb,
                                             float* __restrict__ w2) {
    int lane = threadIdx.x & 63;
    int wv = threadIdx.x >> 6;
    int k = blockIdx.x * 4 + wv;
    const float4 c = *(const float4*)(cb + (size_t)k * DIM + lane * 4);
    float s = c.x * c.x + c.y * c.y + c.z * c.z + c.w * c.w;
    #pragma unroll
    for (int m = 32; m >= 1; m >>= 1) s += __shfl_xor(s, m);
    if (lane == 0) w2[k] = s;
}

// ---------------------------------------------------------------------------
// MFMA distance-GEMM + argmin. Tile 128 tokens x 128 codes, BK=32 over D=256.
// 4 waves in 2x2; each wave: 4x4 frags of 16x16x32 bf16 MFMA.
// Cross-block merge via atomicMin on packed (sortable_score<<32 | col).
__global__ __launch_bounds__(256) void vq_gemm(const unsigned short* __restrict__ zb,
                                               const unsigned short* __restrict__ cbb,
                                               const float* __restrict__ w2,
                                               unsigned long long* __restrict__ packed) {
    __shared__ unsigned short za[128 * 32];
    __shared__ unsigned short ca[128 * 32];
    __shared__ unsigned long long smin[128];

    const int tid  = threadIdx.x;
    const int lane = tid & 63;
    const int w    = tid >> 6;
    const int wr   = w >> 1, wc = w & 1;
    const int t0   = blockIdx.y * 128;   // token base
    const int c0   = blockIdx.x * 128;   // code base
    const int quad = lane >> 4;
    const int l15  = lane & 15;

    if (tid < 128) smin[tid] = ~0ULL;

    f32x4 acc[4][4];
    #pragma unroll
    for (int i = 0; i < 4; ++i)
        #pragma unroll
        for (int j = 0; j < 4; ++j)
            acc[i][j] = (f32x4){0.0f, 0.0f, 0.0f, 0.0f};

    const int srow   = lane >> 2;        // 0..15: row within 16-row stripe
    const int schunk = (lane & 3) * 8;   // bf16-element offset within row

    for (int kb = 0; kb < DIM; kb += 32) {
        __syncthreads();   // previous readers done (and smin init published)
        // stage A: wave w stages tile rows [w*32, w*32+32)
        #pragma unroll
        for (int q = 0; q < 2; ++q) {
            int rr = w * 32 + q * 16;
            __builtin_amdgcn_global_load_lds(
                (const __attribute__((address_space(1))) void*)(zb + (size_t)(t0 + rr + srow) * DIM + kb + schunk),
                (__attribute__((address_space(3))) void*)(za + rr * 32),
                16, 0, 0);
            __builtin_amdgcn_global_load_lds(
                (const __attribute__((address_space(1))) void*)(cbb + (size_t)(c0 + rr + srow) * DIM + kb + schunk),
                (__attribute__((address_space(3))) void*)(ca + rr * 32),
                16, 0, 0);
        }
        __syncthreads();   // staging complete (implies vmcnt(0) drain)

        s16x8 af[4], bfr[4];
        #pragma unroll
        for (int i = 0; i < 4; ++i)
            af[i] = *(const s16x8*)(za + (wr * 64 + i * 16 + l15) * 32 + quad * 8);
        #pragma unroll
        for (int j = 0; j < 4; ++j)
            bfr[j] = *(const s16x8*)(ca + (wc * 64 + j * 16 + l15) * 32 + quad * 8);
        #pragma unroll
        for (int i = 0; i < 4; ++i)
            #pragma unroll
            for (int j = 0; j < 4; ++j)
                acc[i][j] = __builtin_amdgcn_mfma_f32_16x16x32_bf16(af[i], bfr[j], acc[i][j], 0, 0, 0);
    }

    // epilogue: score = w2[col] - 2*dot ; argmin with tie -> lower col
    const int colbase = c0 + wc * 64 + l15;
    float w2v[4];
    #pragma unroll
    for (int j = 0; j < 4; ++j) w2v[j] = w2[colbase + j * 16];

    #pragma unroll
    for (int i = 0; i < 4; ++i) {
        #pragma unroll
        for (int r = 0; r < 4; ++r) {
            float best = FLT_MAX; int bcol = 0x7FFFFFFF;
            #pragma unroll
            for (int j = 0; j < 4; ++j) {
                float s = fmaf(-2.0f, acc[i][j][r], w2v[j]);
                if (s < best) { best = s; bcol = colbase + j * 16; }  // ascending cols: strict < keeps lowest
            }
            // reduce across the 16 lanes of this quad (xor masks 1,2,4,8 stay in-quad)
            #pragma unroll
            for (int m = 1; m < 16; m <<= 1) {
                float ob = __shfl_xor(best, m);
                int   oi = __shfl_xor(bcol, m);
                if (ob < best || (ob == best && oi < bcol)) { best = ob; bcol = oi; }
            }
            if (l15 == 0) {
                unsigned int fb = __float_as_uint(best);
                fb = (fb & 0x80000000u) ? ~fb : (fb | 0x80000000u);   // monotonic float key
                unsigned long long key = ((unsigned long long)fb << 32) | (unsigned int)bcol;
                atomicMin(&smin[wr * 64 + i * 16 + quad * 4 + r], key);
            }
        }
    }
    __syncthreads();
    if (tid < 128) atomicMin(packed + (size_t)(t0 + tid), smin[tid]);
}

// ---------------------------------------------------------------------------
// gather z_q (exact fp32 codebook rows) + loss partial + usage flags
__global__ __launch_bounds__(256) void vq_gather(const float* __restrict__ z_e,
                                                 const float* __restrict__ cb,
                                                 const unsigned long long* __restrict__ packed,
                                                 float* __restrict__ out,
                                                 int* __restrict__ flags) {
    __shared__ float wls[4];
    const int tid = threadIdx.x;
    const int lane = tid & 63;
    const int wv = tid >> 6;
    const int tblock = blockIdx.x * 64;

    float lsum = 0.0f;
    for (int t = wv; t < 64; t += 4) {
        int tok = tblock + t;
        int k = (int)(unsigned int)(packed[tok] & 0xFFFFFFFFull);
        if (lane == 0) flags[k] = 1;   // benign race, all write 1
        float4 c = *(const float4*)(cb + (size_t)k * DIM + lane * 4);
        float4 z = *(const float4*)(z_e + (size_t)tok * DIM + lane * 4);
        float dx = z.x - c.x, dy = z.y - c.y, dz = z.z - c.z, dw = z.w - c.w;
        lsum += dx * dx + dy * dy + dz * dz + dw * dw;
        *(float4*)(out + (size_t)tok * DIM + lane * 4) = c;
    }
    #pragma unroll
    for (int m = 32; m >= 1; m >>= 1) lsum += __shfl_xor(lsum, m);
    if (lane == 0) wls[wv] = lsum;
    __syncthreads();
    if (tid == 0) {
        float blocksum = wls[0] + wls[1] + wls[2] + wls[3];
        // loss = codebook + 0.25*commitment = 1.25 * mean(diff^2)
        atomicAdd(out + LOSS_IDX, blocksum * (1.25f / (float)LOSS_IDX));
    }
}

// ---------------------------------------------------------------------------
__global__ __launch_bounds__(256) void vq_usage(const int* __restrict__ flags,
                                                float* __restrict__ out) {
    __shared__ int ws[4];
    int tid = threadIdx.x;
    int s = 0;
    for (int i = tid; i < KC; i += 256) s += flags[i];
    #pragma unroll
    for (int m = 32; m >= 1; m >>= 1) s += __shfl_xor(s, m);
    if ((tid & 63) == 0) ws[tid >> 6] = s;
    __syncthreads();
    if (tid == 0) out[USAGE_IDX] = (float)(ws[0] + ws[1] + ws[2] + ws[3]) / (float)KC;
}

// ---------------------------------------------------------------------------
extern "C" void kernel_launch(void* const* d_in, const int* in_sizes, int n_in,
                              void* d_out, int out_size, void* d_ws, size_t ws_size,
                              hipStream_t stream) {
    (void)in_sizes; (void)n_in; (void)out_size; (void)ws_size;
    const float* z_e = (const float*)d_in[0];
    const float* cb  = (const float*)d_in[1];
    float* out = (float*)d_out;

    char* ws = (char*)d_ws;
    unsigned long long* packed = (unsigned long long*)(ws + WS_PACKED);
    float* w2    = (float*)(ws + WS_W2);
    int*   flags = (int*)(ws + WS_FLAGS);
    unsigned short* z_bf  = (unsigned short*)(ws + WS_ZBF);
    unsigned short* cb_bf = (unsigned short*)(ws + WS_CBF);

    vq_init<<<T_TOTAL / 256, 256, 0, stream>>>(packed, flags, out);
    vq_cvt<<<(T_TOTAL * DIM) / (256 * 8), 256, 0, stream>>>(z_e, z_bf);    // 4096 blocks
    vq_cvt<<<(KC * DIM) / (256 * 8), 256, 0, stream>>>(cb, cb_bf);         // 1024 blocks
    vq_w2<<<KC / 4, 256, 0, stream>>>(cb, w2);
    dim3 g(KC / 128, T_TOTAL / 128);   // x = code tile (64), y = token tile (256)
    vq_gemm<<<g, 256, 0, stream>>>(z_bf, cb_bf, w2, packed);
    vq_gather<<<T_TOTAL / 64, 256, 0, stream>>>(z_e, cb, packed, out, flags);
    vq_usage<<<1, 256, 0, stream>>>(flags, out);
}

// Round 3
// 280.823 us; speedup vs baseline: 8.1062x; 1.4497x over previous
//
#include <hip/hip_runtime.h>
#include <float.h>

#define T_TOTAL 32768
#define KC      8192
#define DIM     256

#define LOSS_IDX  ((size_t)T_TOTAL * DIM)      // 8388608
#define USAGE_IDX (LOSS_IDX + 1)

typedef short s16x8 __attribute__((ext_vector_type(8)));
typedef float f32x4 __attribute__((ext_vector_type(4)));

// ws layout (bytes):
#define WS_W2    0                       // f32[8192]
#define WS_FLAGS 32768                   // i32[8192]
#define WS_ZBF   65536                   // u16[32768*256] = 16 MB
#define WS_CBF   (65536 + 16777216)      // u16[8192*256]  = 4 MB

__device__ __forceinline__ unsigned short f2bf(float f) {
    unsigned int u = __float_as_uint(f);
    u += 0x7FFFu + ((u >> 16) & 1u);   // RTNE
    return (unsigned short)(u >> 16);
}

// ---------------------------------------------------------------------------
// prep: z->bf16 (blocks 0..4095), cb->bf16 + w2 (blocks 4096..5119),
// flags zero (first 32 blocks), scalar outputs zero (block 0).
__global__ __launch_bounds__(256) void vq_prep(const float* __restrict__ z_e,
                                               const float* __restrict__ cb,
                                               unsigned short* __restrict__ zb,
                                               unsigned short* __restrict__ cbb,
                                               float* __restrict__ w2,
                                               int* __restrict__ flags,
                                               float* __restrict__ out) {
    const int blk = blockIdx.x, tid = threadIdx.x;
    if (blk < 4096) {
        size_t i = ((size_t)blk * 256 + tid) * 8;
        float4 a = *(const float4*)(z_e + i);
        float4 b = *(const float4*)(z_e + i + 4);
        uint4 o;
        o.x = (unsigned)f2bf(a.x) | ((unsigned)f2bf(a.y) << 16);
        o.y = (unsigned)f2bf(a.z) | ((unsigned)f2bf(a.w) << 16);
        o.z = (unsigned)f2bf(b.x) | ((unsigned)f2bf(b.y) << 16);
        o.w = (unsigned)f2bf(b.z) | ((unsigned)f2bf(b.w) << 16);
        *(uint4*)(zb + i) = o;
        if (blk < 32) flags[blk * 256 + tid] = 0;
        if (blk == 0 && tid == 0) { out[LOSS_IDX] = 0.0f; out[USAGE_IDX] = 0.0f; }
    } else {
        size_t base = (size_t)(blk - 4096) * 2048;
        size_t i = base + (size_t)tid * 8;
        float4 a = *(const float4*)(cb + i);
        float4 b = *(const float4*)(cb + i + 4);
        uint4 o;
        o.x = (unsigned)f2bf(a.x) | ((unsigned)f2bf(a.y) << 16);
        o.y = (unsigned)f2bf(a.z) | ((unsigned)f2bf(a.w) << 16);
        o.z = (unsigned)f2bf(b.x) | ((unsigned)f2bf(b.y) << 16);
        o.w = (unsigned)f2bf(b.z) | ((unsigned)f2bf(b.w) << 16);
        *(uint4*)(cbb + i) = o;
        // exact fp32 w2: 32 lanes cover one 256-dim row (8 elems each)
        float s = a.x * a.x + a.y * a.y + a.z * a.z + a.w * a.w
                + b.x * b.x + b.y * b.y + b.z * b.z + b.w * b.w;
        #pragma unroll
        for (int m = 1; m <= 16; m <<= 1) s += __shfl_xor(s, m);
        if ((tid & 31) == 0) w2[(blk - 4096) * 8 + (tid >> 5)] = s;
    }
}

// ---------------------------------------------------------------------------
// main: block = 128 tokens x ALL 8192 codes (grid 256 = 1 block/CU).
// 512 threads = 8 waves; wave w: token quarter wr=w>>1 (32 tokens, 2 stripes),
// code half wc=w&1 (64 codes of each 128-chunk). A-frags in registers for the
// whole kernel; B staged in swizzled LDS per 128-wide K window. Register
// argmin folded per chunk; LDS u64 atomicMin merges wc halves; fused gather.
__global__ __launch_bounds__(512, 2) void vq_main(const unsigned short* __restrict__ zb,
                                                  const unsigned short* __restrict__ cbb,
                                                  const float* __restrict__ w2g,
                                                  const float* __restrict__ z_e,
                                                  const float* __restrict__ cb,
                                                  float* __restrict__ out,
                                                  int* __restrict__ flags) {
    __shared__ unsigned short ca[128 * 128];   // 128 codes x 128 k (swizzled), 32 KB
    __shared__ unsigned long long smin[128];
    __shared__ float wls[8];

    const int tid  = threadIdx.x;
    const int lane = tid & 63;
    const int w    = tid >> 6;        // 0..7
    const int wr   = w >> 1;          // token quarter
    const int wc   = w & 1;           // code half
    const int quad = lane >> 4;
    const int l15  = lane & 15;
    const int t0   = blockIdx.x * 128;

    if (tid < 128) smin[tid] = ~0ULL;

    // one-time: A fragments for this wave's 32 tokens, full D=256, into 64 VGPRs
    s16x8 af[2][8];
    #pragma unroll
    for (int i = 0; i < 2; ++i)
        #pragma unroll
        for (int ks = 0; ks < 8; ++ks)
            af[i][ks] = *(const s16x8*)(zb + (size_t)(t0 + wr * 32 + i * 16 + l15) * DIM + ks * 32 + quad * 8);

    float best[2][4];
    int   bidx[2][4];
    #pragma unroll
    for (int i = 0; i < 2; ++i)
        #pragma unroll
        for (int r = 0; r < 4; ++r) { best[i][r] = FLT_MAX; bidx[i][r] = 0x7FFFFFFF; }

    for (int c0 = 0; c0 < KC; c0 += 128) {
        f32x4 acc[2][4];
        #pragma unroll
        for (int i = 0; i < 2; ++i)
            #pragma unroll
            for (int j = 0; j < 4; ++j) acc[i][j] = (f32x4){0.f, 0.f, 0.f, 0.f};

        #pragma unroll
        for (int kw = 0; kw < 2; ++kw) {          // two 128-wide K windows
            __syncthreads();                       // prev readers done
            #pragma unroll
            for (int r = 0; r < 4; ++r) {          // stage 32 KB: 1 issue/thread/round
                int rowbase = r * 32 + w * 4;      // wave-uniform
                int row = rowbase + (lane >> 4);
                int src_c = (lane & 15) ^ (row & 15);   // xor swizzle
                __builtin_amdgcn_global_load_lds(
                    (const __attribute__((address_space(1))) void*)(cbb + (size_t)(c0 + row) * DIM + kw * 128 + src_c * 8),
                    (__attribute__((address_space(3))) void*)(ca + rowbase * 128),
                    16, 0, 0);
            }
            __syncthreads();                       // staging complete

            #pragma unroll
            for (int kk = 0; kk < 4; ++kk) {
                s16x8 bfr[4];
                #pragma unroll
                for (int j = 0; j < 4; ++j) {
                    int row = wc * 64 + j * 16 + l15;
                    int slot = (kk * 4 + quad) ^ l15;   // matches staging swizzle (row&15 == l15)
                    bfr[j] = *(const s16x8*)(ca + row * 128 + slot * 8);
                }
                #pragma unroll
                for (int i = 0; i < 2; ++i)
                    #pragma unroll
                    for (int j = 0; j < 4; ++j)
                        acc[i][j] = __builtin_amdgcn_mfma_f32_16x16x32_bf16(af[i][kw * 4 + kk], bfr[j], acc[i][j], 0, 0, 0);
            }
        }

        // fold chunk into running argmin: score = w2[col] - 2*dot
        #pragma unroll
        for (int j = 0; j < 4; ++j) {
            int col = c0 + wc * 64 + j * 16 + l15;
            float w2v = w2g[col];
            #pragma unroll
            for (int i = 0; i < 2; ++i)
                #pragma unroll
                for (int r = 0; r < 4; ++r) {
                    float s = fmaf(-2.0f, acc[i][j][r], w2v);
                    if (s < best[i][r]) { best[i][r] = s; bidx[i][r] = col; }  // ascending col: < keeps lowest
                }
        }
    }

    // cross-lane argmin (16 lanes of quad share a token row), then merge wc halves in LDS
    #pragma unroll
    for (int i = 0; i < 2; ++i)
        #pragma unroll
        for (int r = 0; r < 4; ++r) {
            float b = best[i][r]; int ix = bidx[i][r];
            #pragma unroll
            for (int m = 1; m < 16; m <<= 1) {
                float ob = __shfl_xor(b, m);
                int   oi = __shfl_xor(ix, m);
                if (ob < b || (ob == b && oi < ix)) { b = ob; ix = oi; }
            }
            if (l15 == 0) {
                unsigned int fb = __float_as_uint(b);
                fb = (fb & 0x80000000u) ? ~fb : (fb | 0x80000000u);   // monotonic key
                unsigned long long key = ((unsigned long long)fb << 32) | (unsigned int)ix;
                atomicMin(&smin[wr * 32 + i * 16 + quad * 4 + r], key);
            }
        }
    __syncthreads();

    // fused gather + loss + flags: wave w -> tokens [w*16, w*16+16)
    float lsum = 0.0f;
    for (int t = w * 16; t < w * 16 + 16; ++t) {
        int tok = t0 + t;
        int k = (int)(unsigned int)(smin[t] & 0xFFFFFFFFull);
        if (lane == 0) flags[k] = 1;   // benign race
        float4 c = *(const float4*)(cb + (size_t)k * DIM + lane * 4);
        float4 z = *(const float4*)(z_e + (size_t)tok * DIM + lane * 4);
        float dx = z.x - c.x, dy = z.y - c.y, dz = z.z - c.z, dw = z.w - c.w;
        lsum += dx * dx + dy * dy + dz * dz + dw * dw;
        *(float4*)(out + (size_t)tok * DIM + lane * 4) = c;
    }
    #pragma unroll
    for (int m = 32; m >= 1; m >>= 1) lsum += __shfl_xor(lsum, m);
    if (lane == 0) wls[w] = lsum;
    __syncthreads();
    if (tid == 0) {
        float bsum = 0.0f;
        #pragma unroll
        for (int q = 0; q < 8; ++q) bsum += wls[q];
        // loss = codebook + 0.25*commitment = 1.25 * mean(diff^2)
        atomicAdd(out + LOSS_IDX, bsum * (1.25f / (float)LOSS_IDX));
    }
}

// ---------------------------------------------------------------------------
__global__ __launch_bounds__(256) void vq_usage(const int* __restrict__ flags,
                                                float* __restrict__ out) {
    __shared__ int ws[4];
    int tid = threadIdx.x;
    int s = 0;
    for (int i = tid; i < KC; i += 256) s += flags[i];
    #pragma unroll
    for (int m = 32; m >= 1; m >>= 1) s += __shfl_xor(s, m);
    if ((tid & 63) == 0) ws[tid >> 6] = s;
    __syncthreads();
    if (tid == 0) out[USAGE_IDX] = (float)(ws[0] + ws[1] + ws[2] + ws[3]) / (float)KC;
}

// ---------------------------------------------------------------------------
extern "C" void kernel_launch(void* const* d_in, const int* in_sizes, int n_in,
                              void* d_out, int out_size, void* d_ws, size_t ws_size,
                              hipStream_t stream) {
    (void)in_sizes; (void)n_in; (void)out_size; (void)ws_size;
    const float* z_e = (const float*)d_in[0];
    const float* cb  = (const float*)d_in[1];
    float* out = (float*)d_out;

    char* ws = (char*)d_ws;
    float* w2    = (float*)(ws + WS_W2);
    int*   flags = (int*)(ws + WS_FLAGS);
    unsigned short* zb  = (unsigned short*)(ws + WS_ZBF);
    unsigned short* cbb = (unsigned short*)(ws + WS_CBF);

    vq_prep<<<4096 + 1024, 256, 0, stream>>>(z_e, cb, zb, cbb, w2, flags, out);
    vq_main<<<T_TOTAL / 128, 512, 0, stream>>>(zb, cbb, w2, z_e, cb, out, flags);
    vq_usage<<<1, 256, 0, stream>>>(flags, out);
}

// Round 4
// 265.467 us; speedup vs baseline: 8.5751x; 1.0578x over previous
//
#include <hip/hip_runtime.h>
#include <float.h>

#define T_TOTAL 32768
#define KC      8192
#define DIM     256

#define LOSS_IDX  ((size_t)T_TOTAL * DIM)      // 8388608
#define USAGE_IDX (LOSS_IDX + 1)

typedef short s16x8 __attribute__((ext_vector_type(8)));
typedef float f32x4 __attribute__((ext_vector_type(4)));

// ws layout (bytes):
#define WS_W2    0                 // f32[8192]
#define WS_FLAGS 32768             // i32[8192]
#define WS_CBF   65536             // u16[8192*256] = 4 MB

__device__ __forceinline__ unsigned short f2bf(float f) {
    unsigned int u = __float_as_uint(f);
    u += 0x7FFFu + ((u >> 16) & 1u);   // RTNE
    return (unsigned short)(u >> 16);
}

// ---------------------------------------------------------------------------
// prep: cb->bf16 + exact fp32 w2; flags zero (blocks 0..31); scalars (block 0)
__global__ __launch_bounds__(256) void vq_prep(const float* __restrict__ cb,
                                               unsigned short* __restrict__ cbb,
                                               float* __restrict__ w2,
                                               int* __restrict__ flags,
                                               float* __restrict__ out) {
    const int blk = blockIdx.x, tid = threadIdx.x;
    size_t i = (size_t)blk * 2048 + (size_t)tid * 8;
    float4 a = *(const float4*)(cb + i);
    float4 b = *(const float4*)(cb + i + 4);
    uint4 o;
    o.x = (unsigned)f2bf(a.x) | ((unsigned)f2bf(a.y) << 16);
    o.y = (unsigned)f2bf(a.z) | ((unsigned)f2bf(a.w) << 16);
    o.z = (unsigned)f2bf(b.x) | ((unsigned)f2bf(b.y) << 16);
    o.w = (unsigned)f2bf(b.z) | ((unsigned)f2bf(b.w) << 16);
    *(uint4*)(cbb + i) = o;
    float s = a.x * a.x + a.y * a.y + a.z * a.z + a.w * a.w
            + b.x * b.x + b.y * b.y + b.z * b.z + b.w * b.w;
    #pragma unroll
    for (int m = 1; m <= 16; m <<= 1) s += __shfl_xor(s, m);
    if ((tid & 31) == 0) w2[blk * 8 + (tid >> 5)] = s;
    if (blk < 32) flags[blk * 256 + tid] = 0;
    if (blk == 0 && tid == 0) { out[LOSS_IDX] = 0.0f; out[USAGE_IDX] = 0.0f; }
}

// ---------------------------------------------------------------------------
// main: block = 128 tokens x all 8192 codes, grid 256 (1 block/CU), 8 waves.
// wave w: wr=w>>2 token half (64 tokens, 4 frags), wc=w&3 code quarter (32).
// A built from fp32 z_e in prologue (128 VGPRs). B double-buffered in LDS,
// prefetch issued after barrier / before compute -> 1 barrier per window,
// vmcnt drain overlapped with a full compute phase.
__global__ __launch_bounds__(512, 2) void vq_main(const unsigned short* __restrict__ cbb,
                                                  const float* __restrict__ w2g,
                                                  const float* __restrict__ z_e,
                                                  const float* __restrict__ cb,
                                                  float* __restrict__ out,
                                                  int* __restrict__ flags) {
    __shared__ unsigned short ca[2][128 * 128];   // 2 x 32 KB
    __shared__ unsigned long long smin[128];
    __shared__ float wls[8];

    const int tid  = threadIdx.x;
    const int lane = tid & 63;
    const int w    = tid >> 6;        // 0..7
    const int wr   = w >> 2;          // token half
    const int wc   = w & 3;           // code quarter
    const int quad = lane >> 4;
    const int l15  = lane & 15;
    const int t0   = blockIdx.x * 128;

    if (tid < 128) smin[tid] = ~0ULL;

    // ---- staging helper (wave-cooperative, 32 KB window) ----
    const int srow_off = lane >> 4;                  // 0..3
    #define STAGE(CHUNK, KW, P)                                                         \
        {                                                                               \
            _Pragma("unroll")                                                           \
            for (int r = 0; r < 4; ++r) {                                               \
                int rowbase = r * 32 + w * 4;                                           \
                int row = rowbase + srow_off;                                           \
                int src_c = l15 ^ (row & 15);                                           \
                __builtin_amdgcn_global_load_lds(                                       \
                    (const __attribute__((address_space(1))) void*)                     \
                        (cbb + (size_t)((CHUNK) * 128 + row) * DIM + (KW) * 128 + src_c * 8), \
                    (__attribute__((address_space(3))) void*)(ca[P] + rowbase * 128),   \
                    16, 0, 0);                                                          \
            }                                                                           \
        }

    // ---- A prologue: fp32 z_e -> bf16 fragments, 128 VGPRs ----
    s16x8 af[4][8];
    #pragma unroll
    for (int i = 0; i < 4; ++i) {
        #pragma unroll
        for (int ks = 0; ks < 8; ++ks) {
            const float* p = z_e + (size_t)(t0 + wr * 64 + i * 16 + l15) * DIM + ks * 32 + quad * 8;
            float4 a = *(const float4*)p;
            float4 b = *(const float4*)(p + 4);
            s16x8 v;
            v[0] = (short)f2bf(a.x); v[1] = (short)f2bf(a.y);
            v[2] = (short)f2bf(a.z); v[3] = (short)f2bf(a.w);
            v[4] = (short)f2bf(b.x); v[5] = (short)f2bf(b.y);
            v[6] = (short)f2bf(b.z); v[7] = (short)f2bf(b.w);
            af[i][ks] = v;
        }
    }

    float best[4][4];
    int   bidx[4][4];
    #pragma unroll
    for (int i = 0; i < 4; ++i)
        #pragma unroll
        for (int r = 0; r < 4; ++r) { best[i][r] = FLT_MAX; bidx[i][r] = 0x7FFFFFFF; }

    STAGE(0, 0, 0);   // prologue prefetch: window 0 -> buf 0

    for (int c = 0; c < 64; ++c) {
        f32x4 acc[4][2];
        #pragma unroll
        for (int i = 0; i < 4; ++i)
            #pragma unroll
            for (int j = 0; j < 2; ++j) acc[i][j] = (f32x4){0.f, 0.f, 0.f, 0.f};

        #pragma unroll
        for (int kw = 0; kw < 2; ++kw) {
            __syncthreads();                    // drains my prefetch of this window (issued 1 window ago)
            // prefetch next window into the other buffer
            if (kw == 0) {
                STAGE(c, 1, 1);
            } else if (c < 63) {
                STAGE(c + 1, 0, 0);
            }
            // compute on buf kw
            #pragma unroll
            for (int kk = 0; kk < 4; ++kk) {
                s16x8 bfr[2];
                #pragma unroll
                for (int j = 0; j < 2; ++j) {
                    int row = wc * 32 + j * 16 + l15;
                    int slot = (kk * 4 + quad) ^ l15;   // matches staging swizzle (row&15 == l15)
                    bfr[j] = *(const s16x8*)(ca[kw] + row * 128 + slot * 8);
                }
                #pragma unroll
                for (int i = 0; i < 4; ++i)
                    #pragma unroll
                    for (int j = 0; j < 2; ++j)
                        acc[i][j] = __builtin_amdgcn_mfma_f32_16x16x32_bf16(af[i][kw * 4 + kk], bfr[j], acc[i][j], 0, 0, 0);
            }
        }

        // fold chunk c into running argmin: score = w2[col] - 2*dot
        #pragma unroll
        for (int j = 0; j < 2; ++j) {
            int col = c * 128 + wc * 32 + j * 16 + l15;
            float w2v = w2g[col];
            #pragma unroll
            for (int i = 0; i < 4; ++i)
                #pragma unroll
                for (int r = 0; r < 4; ++r) {
                    float s = fmaf(-2.0f, acc[i][j][r], w2v);
                    if (s < best[i][r]) { best[i][r] = s; bidx[i][r] = col; }  // ascending col: < keeps lowest
                }
        }
    }

    // cross-lane argmin over the 16 cols held per token row, then merge quarters
    #pragma unroll
    for (int i = 0; i < 4; ++i)
        #pragma unroll
        for (int r = 0; r < 4; ++r) {
            float b = best[i][r]; int ix = bidx[i][r];
            #pragma unroll
            for (int m = 1; m < 16; m <<= 1) {
                float ob = __shfl_xor(b, m);
                int   oi = __shfl_xor(ix, m);
                if (ob < b || (ob == b && oi < ix)) { b = ob; ix = oi; }
            }
            if (l15 == 0) {
                unsigned int fb = __float_as_uint(b);
                fb = (fb & 0x80000000u) ? ~fb : (fb | 0x80000000u);   // monotonic key
                unsigned long long key = ((unsigned long long)fb << 32) | (unsigned int)ix;
                atomicMin(&smin[wr * 64 + i * 16 + quad * 4 + r], key);
            }
        }
    __syncthreads();

    // fused gather + loss + flags: wave w -> tokens [w*16, w*16+16)
    float lsum = 0.0f;
    for (int t = w * 16; t < w * 16 + 16; ++t) {
        int tok = t0 + t;
        int k = (int)(unsigned int)(smin[t] & 0xFFFFFFFFull);
        if (lane == 0) flags[k] = 1;   // benign race
        float4 cv = *(const float4*)(cb + (size_t)k * DIM + lane * 4);
        float4 zv = *(const float4*)(z_e + (size_t)tok * DIM + lane * 4);
        float dx = zv.x - cv.x, dy = zv.y - cv.y, dz = zv.z - cv.z, dw = zv.w - cv.w;
        lsum += dx * dx + dy * dy + dz * dz + dw * dw;
        *(float4*)(out + (size_t)tok * DIM + lane * 4) = cv;
    }
    #pragma unroll
    for (int m = 32; m >= 1; m >>= 1) lsum += __shfl_xor(lsum, m);
    if (lane == 0) wls[w] = lsum;
    __syncthreads();
    if (tid == 0) {
        float bsum = 0.0f;
        #pragma unroll
        for (int q = 0; q < 8; ++q) bsum += wls[q];
        // loss = codebook + 0.25*commitment = 1.25 * mean(diff^2)
        atomicAdd(out + LOSS_IDX, bsum * (1.25f / (float)LOSS_IDX));
    }
}

// ---------------------------------------------------------------------------
__global__ __launch_bounds__(256) void vq_usage(const int* __restrict__ flags,
                                                float* __restrict__ out) {
    __shared__ int ws[4];
    int tid = threadIdx.x;
    int s = 0;
    for (int i = tid; i < KC; i += 256) s += flags[i];
    #pragma unroll
    for (int m = 32; m >= 1; m >>= 1) s += __shfl_xor(s, m);
    if ((tid & 63) == 0) ws[tid >> 6] = s;
    __syncthreads();
    if (tid == 0) out[USAGE_IDX] = (float)(ws[0] + ws[1] + ws[2] + ws[3]) / (float)KC;
}

// ---------------------------------------------------------------------------
extern "C" void kernel_launch(void* const* d_in, const int* in_sizes, int n_in,
                              void* d_out, int out_size, void* d_ws, size_t ws_size,
                              hipStream_t stream) {
    (void)in_sizes; (void)n_in; (void)out_size; (void)ws_size;
    const float* z_e = (const float*)d_in[0];
    const float* cb  = (const float*)d_in[1];
    float* out = (float*)d_out;

    char* ws = (char*)d_ws;
    float* w2    = (float*)(ws + WS_W2);
    int*   flags = (int*)(ws + WS_FLAGS);
    unsigned short* cbb = (unsigned short*)(ws + WS_CBF);

    vq_prep<<<KC / 8, 256, 0, stream>>>(cb, cbb, w2, flags, out);
    vq_main<<<T_TOTAL / 128, 512, 0, stream>>>(cbb, w2, z_e, cb, out, flags);
    vq_usage<<<1, 256, 0, stream>>>(flags, out);
}

// Round 6
// 253.669 us; speedup vs baseline: 8.9739x; 1.0465x over previous
//
#include <hip/hip_runtime.h>
#include <float.h>

#define T_TOTAL 32768
#define KC      8192
#define DIM     256

#define LOSS_IDX  ((size_t)T_TOTAL * DIM)      // 8388608
#define USAGE_IDX (LOSS_IDX + 1)

typedef short s16x8 __attribute__((ext_vector_type(8)));
typedef float f32x4 __attribute__((ext_vector_type(4)));

// ws layout (bytes):
#define WS_W2    0                 // f32[8192]
#define WS_FLAGS 32768             // i32[8192]
#define WS_CBF   65536             // u16[8192*256] = 4 MB

__device__ __forceinline__ unsigned short f2bf(float f) {
    unsigned int u = __float_as_uint(f);
    u += 0x7FFFu + ((u >> 16) & 1u);   // RTNE
    return (unsigned short)(u >> 16);
}

// ---------------------------------------------------------------------------
// prep: cb->bf16 + exact fp32 w2; flags zero (blocks 0..31); scalars (block 0)
__global__ __launch_bounds__(256) void vq_prep(const float* __restrict__ cb,
                                               unsigned short* __restrict__ cbb,
                                               float* __restrict__ w2,
                                               int* __restrict__ flags,
                                               float* __restrict__ out) {
    const int blk = blockIdx.x, tid = threadIdx.x;
    size_t i = (size_t)blk * 2048 + (size_t)tid * 8;
    float4 a = *(const float4*)(cb + i);
    float4 b = *(const float4*)(cb + i + 4);
    uint4 o;
    o.x = (unsigned)f2bf(a.x) | ((unsigned)f2bf(a.y) << 16);
    o.y = (unsigned)f2bf(a.z) | ((unsigned)f2bf(a.w) << 16);
    o.z = (unsigned)f2bf(b.x) | ((unsigned)f2bf(b.y) << 16);
    o.w = (unsigned)f2bf(b.z) | ((unsigned)f2bf(b.w) << 16);
    *(uint4*)(cbb + i) = o;
    float s = a.x * a.x + a.y * a.y + a.z * a.z + a.w * a.w
            + b.x * b.x + b.y * b.y + b.z * b.z + b.w * b.w;
    #pragma unroll
    for (int m = 1; m <= 16; m <<= 1) s += __shfl_xor(s, m);
    if ((tid & 31) == 0) w2[blk * 8 + (tid >> 5)] = s;
    if (blk < 32) flags[blk * 256 + tid] = 0;
    if (blk == 0 && tid == 0) { out[LOSS_IDX] = 0.0f; out[USAGE_IDX] = 0.0f; }
}

// ---------------------------------------------------------------------------
// main: block = 128 tokens x all 8192 codes, grid 256 (1 block/CU), 8 waves.
// wave w: wr=w>>2 token half (64 tokens, 4 A-frags), wc=w&3 code quarter (32).
// BARRIER-FREE K-loop with wave-private LDS double buffers. Ordering per
// window: s_waitcnt vmcnt(0) [drains ONLY loads issued one window ago] ->
// ds_read fragments -> issue prefetch of next window -> 32 MFMAs.
// NOTE: global_load_lds->ds_read aliasing is NOT tracked by the compiler;
// the explicit vmcnt wait is load-bearing (round-5 failure without it).
__global__ __launch_bounds__(512, 2) void vq_main(const unsigned short* __restrict__ cbb,
                                                  const float* __restrict__ w2g,
                                                  const float* __restrict__ z_e,
                                                  const float* __restrict__ cb,
                                                  float* __restrict__ out,
                                                  int* __restrict__ flags) {
    __shared__ unsigned short ca[16][4096];     // [wave*2+parity][8 KB] = 128 KB
    __shared__ unsigned long long smin[128];
    __shared__ float wls[8];

    const int tid  = threadIdx.x;
    const int lane = tid & 63;
    const int w    = tid >> 6;        // 0..7
    const int wr   = w >> 2;          // token half
    const int wc   = w & 3;           // code quarter
    const int quad = lane >> 4;
    const int l15  = lane & 15;
    const int t0   = blockIdx.x * 128;

    if (tid < 128) smin[tid] = ~0ULL;
    __syncthreads();                  // smin published before any wave's epilogue

    // wave-private staging: window WIN (0..127) covers chunk WIN>>1, k-half WIN&1.
    // lane l -> local row lr = q*4 + l/16 (0..31), LDS slot l%16, swizzled source.
    const int lrow_off = lane >> 4;   // 0..3
    #define STAGE(WIN, P)                                                               \
        {                                                                               \
            int _c  = (WIN) >> 1;                                                       \
            int _kw = (WIN) & 1;                                                        \
            _Pragma("unroll")                                                           \
            for (int q = 0; q < 8; ++q) {                                               \
                int lr = q * 4 + lrow_off;                                              \
                int chunk = l15 ^ (lr & 15);                                            \
                __builtin_amdgcn_global_load_lds(                                       \
                    (const __attribute__((address_space(1))) void*)                     \
                        (cbb + (size_t)(_c * 128 + wc * 32 + lr) * DIM + _kw * 128 + chunk * 8), \
                    (__attribute__((address_space(3))) void*)(&ca[w * 2 + (P)][q * 512]), \
                    16, 0, 0);                                                          \
            }                                                                           \
        }

    // ---- A prologue: fp32 z_e -> bf16 fragments (held in regs all kernel) ----
    STAGE(0, 0);   // overlap window-0 staging with A build
    s16x8 af[4][8];
    #pragma unroll
    for (int i = 0; i < 4; ++i) {
        #pragma unroll
        for (int ks = 0; ks < 8; ++ks) {
            const float* p = z_e + (size_t)(t0 + wr * 64 + i * 16 + l15) * DIM + ks * 32 + quad * 8;
            float4 a = *(const float4*)p;
            float4 b = *(const float4*)(p + 4);
            s16x8 v;
            v[0] = (short)f2bf(a.x); v[1] = (short)f2bf(a.y);
            v[2] = (short)f2bf(a.z); v[3] = (short)f2bf(a.w);
            v[4] = (short)f2bf(b.x); v[5] = (short)f2bf(b.y);
            v[6] = (short)f2bf(b.z); v[7] = (short)f2bf(b.w);
            af[i][ks] = v;
        }
    }

    float best[4][4];
    int   bidx[4][4];
    #pragma unroll
    for (int i = 0; i < 4; ++i)
        #pragma unroll
        for (int r = 0; r < 4; ++r) { best[i][r] = FLT_MAX; bidx[i][r] = 0x7FFFFFFF; }

    for (int c = 0; c < 64; ++c) {
        f32x4 acc[4][2];
        #pragma unroll
        for (int i = 0; i < 4; ++i)
            #pragma unroll
            for (int j = 0; j < 2; ++j) acc[i][j] = (f32x4){0.f, 0.f, 0.f, 0.f};

        #pragma unroll
        for (int kw = 0; kw < 2; ++kw) {
            const int win = c * 2 + kw;
            const unsigned short* buf = ca[w * 2 + (win & 1)];
            // LOAD-BEARING: wait for this window's staging (issued 1 window ago).
            // vmcnt(0), lgkmcnt/expcnt unconstrained: imm = 0x0f70 (gfx9 encoding).
            __builtin_amdgcn_s_waitcnt(0x0f70);
            // read this window's 8 B-fragments
            s16x8 bfr[4][2];
            #pragma unroll
            for (int kk = 0; kk < 4; ++kk)
                #pragma unroll
                for (int j = 0; j < 2; ++j) {
                    int row = j * 16 + l15;                 // local row in wave's 32 codes
                    int slot = (kk * 4 + quad) ^ l15;       // undo staging swizzle
                    bfr[kk][j] = *(const s16x8*)(buf + row * 128 + slot * 8);
                }
            // prefetch next window into the other private buffer
            if (win < 127) STAGE(win + 1, (win + 1) & 1);
            // 32 MFMAs on current window
            #pragma unroll
            for (int kk = 0; kk < 4; ++kk)
                #pragma unroll
                for (int i = 0; i < 4; ++i)
                    #pragma unroll
                    for (int j = 0; j < 2; ++j)
                        acc[i][j] = __builtin_amdgcn_mfma_f32_16x16x32_bf16(af[i][kw * 4 + kk], bfr[kk][j], acc[i][j], 0, 0, 0);
        }

        // fold chunk c into running argmin: score = w2[col] - 2*dot
        #pragma unroll
        for (int j = 0; j < 2; ++j) {
            int col = c * 128 + wc * 32 + j * 16 + l15;
            float w2v = w2g[col];
            #pragma unroll
            for (int i = 0; i < 4; ++i)
                #pragma unroll
                for (int r = 0; r < 4; ++r) {
                    float s = fmaf(-2.0f, acc[i][j][r], w2v);
                    if (s < best[i][r]) { best[i][r] = s; bidx[i][r] = col; }  // ascending col: < keeps lowest
                }
        }
    }

    // cross-lane argmin over the 16 cols held per token row, then merge quarters
    #pragma unroll
    for (int i = 0; i < 4; ++i)
        #pragma unroll
        for (int r = 0; r < 4; ++r) {
            float b = best[i][r]; int ix = bidx[i][r];
            #pragma unroll
            for (int m = 1; m < 16; m <<= 1) {
                float ob = __shfl_xor(b, m);
                int   oi = __shfl_xor(ix, m);
                if (ob < b || (ob == b && oi < ix)) { b = ob; ix = oi; }
            }
            if (l15 == 0) {
                unsigned int fb = __float_as_uint(b);
                fb = (fb & 0x80000000u) ? ~fb : (fb | 0x80000000u);   // monotonic key
                unsigned long long key = ((unsigned long long)fb << 32) | (unsigned int)ix;
                atomicMin(&smin[wr * 64 + i * 16 + quad * 4 + r], key);
            }
        }
    __syncthreads();   // all waves' argmin merged before gather

    // fused gather + loss + flags: wave w -> tokens [w*16, w*16+16)
    float lsum = 0.0f;
    for (int t = w * 16; t < w * 16 + 16; ++t) {
        int tok = t0 + t;
        int k = (int)(unsigned int)(smin[t] & 0xFFFFFFFFull);
        if (lane == 0) flags[k] = 1;   // benign race
        float4 cv = *(const float4*)(cb + (size_t)k * DIM + lane * 4);
        float4 zv = *(const float4*)(z_e + (size_t)tok * DIM + lane * 4);
        float dx = zv.x - cv.x, dy = zv.y - cv.y, dz = zv.z - cv.z, dw = zv.w - cv.w;
        lsum += dx * dx + dy * dy + dz * dz + dw * dw;
        *(float4*)(out + (size_t)tok * DIM + lane * 4) = cv;
    }
    #pragma unroll
    for (int m = 32; m >= 1; m >>= 1) lsum += __shfl_xor(lsum, m);
    if (lane == 0) wls[w] = lsum;
    __syncthreads();
    if (tid == 0) {
        float bsum = 0.0f;
        #pragma unroll
        for (int q = 0; q < 8; ++q) bsum += wls[q];
        // loss = codebook + 0.25*commitment = 1.25 * mean(diff^2)
        atomicAdd(out + LOSS_IDX, bsum * (1.25f / (float)LOSS_IDX));
    }
}

// ---------------------------------------------------------------------------
__global__ __launch_bounds__(256) void vq_usage(const int* __restrict__ flags,
                                                float* __restrict__ out) {
    __shared__ int ws[4];
    int tid = threadIdx.x;
    int s = 0;
    for (int i = tid; i < KC; i += 256) s += flags[i];
    #pragma unroll
    for (int m = 32; m >= 1; m >>= 1) s += __shfl_xor(s, m);
    if ((tid & 63) == 0) ws[tid >> 6] = s;
    __syncthreads();
    if (tid == 0) out[USAGE_IDX] = (float)(ws[0] + ws[1] + ws[2] + ws[3]) / (float)KC;
}

// ---------------------------------------------------------------------------
extern "C" void kernel_launch(void* const* d_in, const int* in_sizes, int n_in,
                              void* d_out, int out_size, void* d_ws, size_t ws_size,
                              hipStream_t stream) {
    (void)in_sizes; (void)n_in; (void)out_size; (void)ws_size;
    const float* z_e = (const float*)d_in[0];
    const float* cb  = (const float*)d_in[1];
    float* out = (float*)d_out;

    char* ws = (char*)d_ws;
    float* w2    = (float*)(ws + WS_W2);
    int*   flags = (int*)(ws + WS_FLAGS);
    unsigned short* cbb = (unsigned short*)(ws + WS_CBF);

    vq_prep<<<KC / 8, 256, 0, stream>>>(cb, cbb, w2, flags, out);
    vq_main<<<T_TOTAL / 128, 512, 0, stream>>>(cbb, w2, z_e, cb, out, flags);
    vq_usage<<<1, 256, 0, stream>>>(flags, out);
}